// Round 1
// 1480.237 us; speedup vs baseline: 1.3800x; 1.3800x over previous
//
#include <hip/hip_runtime.h>
#include <hip/hip_bf16.h>

#define DM 200
#define DIE 400
#define LSEQ 256
#define NB 256

typedef __hip_bfloat16 bf16;
typedef const float* fp;
typedef __attribute__((ext_vector_type(8))) short short8;
typedef __attribute__((ext_vector_type(4))) float f32x4;

__device__ __forceinline__ float b2f(bf16 x) { return __bfloat162float(x); }
__device__ __forceinline__ bf16  f2b(float x) { return __float2bfloat16(x); }

// f32 -> bf16 bits (round-to-nearest-even)
__device__ __forceinline__ unsigned short f2bbits(float f) {
    union { float f; unsigned int u; } c; c.f = f;
    unsigned int u = c.u;
    unsigned int r = (u + 0x7fffu + ((u >> 16) & 1u)) >> 16;
    return (unsigned short)r;
}
__device__ __forceinline__ unsigned short ldb(const float* p) { return f2bbits(*p); }
__device__ __forceinline__ unsigned short ldb(const bf16* p) { return *(const unsigned short*)p; }
__device__ __forceinline__ void stf(float* p, float v) { *p = v; }
__device__ __forceinline__ void stf(bf16* p, float v) { *p = f2b(v); }

// ---------------- MFMA NT GEMM: C[m,n] = sum_k A[m,k]*W[n,k] (+epilogue) ----------------
// Block tile 128(m) x 128(n), K-step 32, 4 waves in 2x2; wave subtile 64x64 = 4x4 MFMA tiles.
// EPI: 0=none, 2=gelu_exact(x+bias), 3=x+bias
template <typename TA, typename TC, int EPI>
__global__ __launch_bounds__(256) void gemm_mfma(const TA* __restrict__ A, int lda,
                                                 const float* __restrict__ W,
                                                 const float* __restrict__ bias,
                                                 TC* __restrict__ C, int ldc,
                                                 int N, int K) {
    constexpr int LS = 40;                       // LDS row stride in shorts (32 + 8 pad, 80 B)
    __shared__ short As[128 * LS];
    __shared__ short Bs[128 * LS];
    const int m0 = blockIdx.x * 128;
    const int n0 = blockIdx.y * 128;
    const int tid = threadIdx.x;
    const int wave = tid >> 6;
    const int lane = tid & 63;
    const int wm = (wave & 1) * 64;
    const int wn = (wave >> 1) * 64;
    const int fm = lane & 15;
    const int quad = lane >> 4;

    f32x4 acc[4][4] = {};

    const int sr = tid >> 1;                     // staging row 0..127
    const int sc = (tid & 1) * 16;               // staging col 0 / 16

    for (int k0 = 0; k0 < K; k0 += 32) {
        // stage A: 128x32 (16 elems/thread)
        {
            const TA* src = A + (size_t)(m0 + sr) * lda + k0 + sc;
            short* dst = As + sr * LS + sc;
            if (k0 + sc + 16 <= K) {
#pragma unroll
                for (int j = 0; j < 16; ++j) dst[j] = (short)ldb(src + j);
            } else {
#pragma unroll
                for (int j = 0; j < 16; ++j)
                    dst[j] = (k0 + sc + j < K) ? (short)ldb(src + j) : (short)0;
            }
        }
        // stage B(W): 128x32 (16 elems/thread), mask n and k
        {
            short* dst = Bs + sr * LS + sc;
            if (n0 + sr < N) {
                const float* src = W + (size_t)(n0 + sr) * K + k0 + sc;
                if (k0 + sc + 16 <= K) {
#pragma unroll
                    for (int j = 0; j < 16; ++j) dst[j] = (short)f2bbits(src[j]);
                } else {
#pragma unroll
                    for (int j = 0; j < 16; ++j)
                        dst[j] = (k0 + sc + j < K) ? (short)f2bbits(src[j]) : (short)0;
                }
            } else {
#pragma unroll
                for (int j = 0; j < 16; ++j) dst[j] = 0;
            }
        }
        __syncthreads();
        short8 af[4], bfr[4];
#pragma unroll
        for (int i = 0; i < 4; ++i)
            af[i] = *(const short8*)(As + (wm + i * 16 + fm) * LS + quad * 8);
#pragma unroll
        for (int j = 0; j < 4; ++j)
            bfr[j] = *(const short8*)(Bs + (wn + j * 16 + fm) * LS + quad * 8);
#pragma unroll
        for (int i = 0; i < 4; ++i)
#pragma unroll
            for (int j = 0; j < 4; ++j)
                acc[i][j] = __builtin_amdgcn_mfma_f32_16x16x32_bf16(af[i], bfr[j], acc[i][j], 0, 0, 0);
        __syncthreads();
    }

    // epilogue: D[m = quad*4 + r][n = fm] per 16x16 tile
#pragma unroll
    for (int j = 0; j < 4; ++j) {
        int n = n0 + wn + j * 16 + fm;
        if (n >= N) continue;
        float bv = (EPI == 2 || EPI == 3) ? bias[n] : 0.f;
#pragma unroll
        for (int i = 0; i < 4; ++i) {
#pragma unroll
            for (int r = 0; r < 4; ++r) {
                int m = m0 + wm + i * 16 + quad * 4 + r;
                float v = acc[i][j][r];
                if (EPI == 2) {
                    v += bv;
                    v = 0.5f * v * (1.f + erff(v * 0.70710678118654752f));
                } else if (EPI == 3) {
                    v += bv;
                }
                stf(&C[(size_t)m * ldc + n], v);
            }
        }
    }
}

// ---------------- causal depthwise conv (k=4) + bias + silu, IN-PLACE on x-half ----------------
__global__ __launch_bounds__(256) void conv_silu_inplace(bf16* __restrict__ xz,
                                                         const float* __restrict__ cw,
                                                         const float* __restrict__ cb,
                                                         int total /* chunkB*DIE */) {
    int idx = blockIdx.x * 256 + threadIdx.x;
    if (idx >= total) return;
    int d = idx % DIE;
    int b = idx / DIE;
    float w0 = cw[d * 4 + 0];
    float w1 = cw[d * 4 + 1];
    float w2 = cw[d * 4 + 2];
    float w3 = cw[d * 4 + 3];
    float bias = cb[d];
    float x0 = 0.f, x1 = 0.f, x2 = 0.f;
    bf16* p = xz + (size_t)b * LSEQ * 800 + d;
    for (int t = 0; t < LSEQ; ++t) {
        float x = b2f(*p);
        float s = bias + w0 * x0 + w1 * x1 + w2 * x2 + w3 * x;
        x0 = x1; x1 = x2; x2 = x;
        // native sigmoid: v_exp_f32 + v_rcp_f32 (error ~1e-6, bf16-dominated)
        float sig = __builtin_amdgcn_rcpf(1.f + __expf(-s));
        *p = f2b(s * sig);
        p += 800;
    }
}

// ---------------- fused selective scan, barrier-free + ping-pong pipelined ----------------
// grid: chunkB*2 blocks, 256 threads (200 active); per-lane channel d, h[16] in regs.
// xdbl row address is wave-uniform -> SGPR-resident scalar loads; t+1 prefetched during t.
// All transcendentals native (v_exp_f32/v_log_f32/v_rcp_f32): this kernel was
// VALU-issue-bound on libm expf/log1pf (~19 calls x ~10 instrs per step).
__global__ __launch_bounds__(256) void scan_kernel(const float* __restrict__ xdbl,
                                                   bf16* __restrict__ xz,
                                                   const float* __restrict__ dt_w,
                                                   const float* __restrict__ dt_b,
                                                   const float* __restrict__ A_log,
                                                   const float* __restrict__ Dw) {
    const int b = blockIdx.x >> 1;
    const int half = blockIdx.x & 1;
    const int tid = threadIdx.x;
    if (tid >= 200) return;            // no barriers below -> legal early exit
    const int d = half * 200 + tid;

    float A2[16], Wr[13];
#pragma unroll
    for (int n = 0; n < 16; ++n) A2[n] = -__expf(A_log[d * 16 + n]);
#pragma unroll
    for (int r = 0; r < 13; ++r) Wr[r] = dt_w[d * 13 + r];
    const float bdt = dt_b[d];
    const float Dv = Dw[d];

    float h[16];
#pragma unroll
    for (int n = 0; n < 16; ++n) h[n] = 0.f;

    const float* __restrict__ rp = xdbl + (size_t)b * LSEQ * 45;   // uniform
    bf16* __restrict__ xp = xz + (size_t)b * LSEQ * 800 + d;

    auto scan_step = [&](const float* cur, float ut, float zv, bf16* outp) {
        float dtv = bdt;
#pragma unroll
        for (int r = 0; r < 13; ++r) dtv += Wr[r] * cur[r];
        // softplus: native exp+log; guard keeps dtv when exp overflows
        float sp = (dtv > 20.f) ? dtv : __logf(1.f + __expf(dtv));
        float du = sp * ut;
        float yv = 0.f;
#pragma unroll
        for (int n = 0; n < 16; ++n) {
            float dA = __expf(sp * A2[n]);
            h[n] = dA * h[n] + du * cur[13 + n];
            yv += h[n] * cur[29 + n];
        }
        yv += ut * Dv;
        float sig = __builtin_amdgcn_rcpf(1.f + __expf(-zv));
        *outp = f2b(yv * zv * sig);
    };

    // prologue: load t=0 into buffer A
    float ca[45], cbuf[45];
#pragma unroll
    for (int j = 0; j < 45; ++j) ca[j] = rp[j];
    float utA = b2f(xp[0]);
    float zvA = b2f(xp[400]);

    for (int t = 0; t < LSEQ; t += 2) {
        // prefetch t+1 into buffer B (independent of step t compute)
#pragma unroll
        for (int j = 0; j < 45; ++j) cbuf[j] = rp[45 + j];
        float utB = b2f(xp[800]);
        float zvB = b2f(xp[1200]);

        scan_step(ca, utA, zvA, xp);

        // prefetch t+2 into buffer A
        if (t + 2 < LSEQ) {
#pragma unroll
            for (int j = 0; j < 45; ++j) ca[j] = rp[90 + j];
            utA = b2f(xp[1600]);
            zvA = b2f(xp[2000]);
        }

        scan_step(cbuf, utB, zvB, xp + 800);

        rp += 90;
        xp += 1600;
    }
}

// ---------------- residual + layernorm over 200 ----------------
__global__ __launch_bounds__(256) void ln_res_kernel(const float* __restrict__ xa,
                                                     const float* __restrict__ xb,
                                                     const float* __restrict__ w,
                                                     const float* __restrict__ bias,
                                                     float* __restrict__ dst, int rows) {
    int wave = threadIdx.x >> 6;
    int lane = threadIdx.x & 63;
    int row = blockIdx.x * 4 + wave;
    if (row >= rows) return;
    const float* pa = xa + (size_t)row * DM;
    const float* pb = xb + (size_t)row * DM;
    float v[4];
    float sum = 0.f, sq = 0.f;
#pragma unroll
    for (int i = 0; i < 4; ++i) {
        int c = lane + i * 64;
        float t = 0.f;
        if (c < DM) t = pa[c] + pb[c];
        v[i] = t;
        sum += t;
        sq += t * t;
    }
#pragma unroll
    for (int off = 32; off > 0; off >>= 1) {
        sum += __shfl_down(sum, off);
        sq += __shfl_down(sq, off);
    }
    sum = __shfl(sum, 0);
    sq = __shfl(sq, 0);
    float mu = sum * (1.f / DM);
    float var = fmaxf(sq * (1.f / DM) - mu * mu, 0.f);
    float rstd = rsqrtf(var + 1e-12f);
    float* pd = dst + (size_t)row * DM;
#pragma unroll
    for (int i = 0; i < 4; ++i) {
        int c = lane + i * 64;
        if (c < DM) pd[c] = (v[i] - mu) * rstd * w[c] + bias[c];
    }
}

// ---------------- output split for a batch chunk (f32 out) ----------------
__global__ __launch_bounds__(256) void write_out_kernel(const float* __restrict__ h,
                                                        float* __restrict__ out,
                                                        int b0, int total /* rc*DM */) {
    int idx = blockIdx.x * 256 + threadIdx.x;
    if (idx >= total) return;
    int d = idx % DM;
    int bl = idx / DM;
    int l = bl % LSEQ;
    int b = b0 + bl / LSEQ;
    float v = h[idx];
    if (l == LSEQ - 1) {
        out[b * DM + d] = v;
    } else {
        out[(size_t)NB * DM + ((size_t)(b * (LSEQ - 1) + l) * DM + d)] = v;
    }
}

extern "C" void kernel_launch(void* const* d_in, const int* in_sizes, int n_in,
                              void* d_out, int out_size, void* d_ws, size_t ws_size,
                              hipStream_t stream) {
    fp emb       = (fp)d_in[0];
    fp in_proj_w = (fp)d_in[2];
    fp conv_w    = (fp)d_in[3];
    fp conv_b    = (fp)d_in[4];
    fp x_proj_w  = (fp)d_in[5];
    fp dt_proj_w = (fp)d_in[6];
    fp dt_proj_b = (fp)d_in[7];
    fp A_log     = (fp)d_in[8];
    fp Dw        = (fp)d_in[9];
    fp out_proj_w= (fp)d_in[10];
    fp ln1_w     = (fp)d_in[11];
    fp ln1_b     = (fp)d_in[12];
    fp ffn_w1    = (fp)d_in[13];
    fp ffn_b1    = (fp)d_in[14];
    fp ffn_w2    = (fp)d_in[15];
    fp ffn_b2    = (fp)d_in[16];
    fp ffn_ln_w  = (fp)d_in[17];
    fp ffn_ln_b  = (fp)d_in[18];

    // per-chunk bytes/row: xz 1600 + xdbl 180 + m 800 + h 800 = 3380; rc = cb*256
    const int cands[8] = {256, 128, 64, 32, 16, 8, 4, 2};
    int cb = 2;
    for (int ci = 0; ci < 8; ++ci) {
        size_t rcx = (size_t)cands[ci] * LSEQ;
        if (rcx * 3380 <= ws_size) { cb = cands[ci]; break; }
    }
    const size_t rc = (size_t)cb * LSEQ;

    bf16*  xz   = (bf16*)d_ws;                 // rc*800
    float* xdbl = (float*)(xz + rc * 800);     // rc*45
    float* m    = xdbl + rc * 45;              // rc*200
    float* h    = m + rc * 200;                // rc*200

    const int rcDM = (int)rc * DM;
    const int gm = (int)rc / 128;              // m-tiles

    for (int b0 = 0; b0 < NB; b0 += cb) {
        const float* emb_chunk = emb + (size_t)b0 * LSEQ * DM;

        for (int i = 0; i < 2; ++i) {
            fp w_in  = in_proj_w + (size_t)i * 800 * 200;
            fp cw    = conv_w + (size_t)i * 400 * 4;
            fp cbp   = conv_b + (size_t)i * 400;
            fp w_xp  = x_proj_w + (size_t)i * 45 * 400;
            fp w_dt  = dt_proj_w + (size_t)i * 400 * 13;
            fp b_dt  = dt_proj_b + (size_t)i * 400;
            fp Ai    = A_log + (size_t)i * 400 * 16;
            fp Di    = Dw + (size_t)i * 400;
            fp w_op  = out_proj_w + (size_t)i * 200 * 400;
            fp l1w   = ln1_w + (size_t)i * 200;
            fp l1b   = ln1_b + (size_t)i * 200;
            fp f1w   = ffn_w1 + (size_t)i * 800 * 200;
            fp f1b   = ffn_b1 + (size_t)i * 800;
            fp f2w   = ffn_w2 + (size_t)i * 200 * 800;
            fp f2b_  = ffn_b2 + (size_t)i * 200;
            fp flw   = ffn_ln_w + (size_t)i * 200;
            fp flb   = ffn_ln_b + (size_t)i * 200;

            const float* hin = (i == 0) ? emb_chunk : h;

            // xz = hin @ in_proj^T   (N=800, K=200)
            gemm_mfma<float, bf16, 0><<<dim3(gm, 7), 256, 0, stream>>>(
                hin, 200, w_in, nullptr, xz, 800, 800, 200);
            // conv + silu in-place on x-half
            conv_silu_inplace<<<(cb * DIE + 255) / 256, 256, 0, stream>>>(xz, cw, cbp, cb * DIE);
            // xdbl = xc @ x_proj^T   (N=45, K=400)
            gemm_mfma<bf16, float, 0><<<dim3(gm, 1), 256, 0, stream>>>(
                xz, 800, w_xp, nullptr, xdbl, 45, 45, 400);
            // fused scan; y in-place on x-half
            scan_kernel<<<cb * 2, 256, 0, stream>>>(xdbl, xz, w_dt, b_dt, Ai, Di);
            // m = y @ out_proj^T   (N=200, K=400)
            gemm_mfma<bf16, float, 0><<<dim3(gm, 2), 256, 0, stream>>>(
                xz, 800, w_op, nullptr, m, 200, 200, 400);
            // h = ln(m + hin)
            ln_res_kernel<<<rc / 4, 256, 0, stream>>>(m, hin, l1w, l1b, h, (int)rc);
            // f1 = gelu(h @ w1^T + b1) -> xz
            gemm_mfma<float, bf16, 2><<<dim3(gm, 7), 256, 0, stream>>>(
                h, 200, f1w, f1b, xz, 800, 800, 200);
            // f2 = f1 @ w2^T + b2 -> m   (N=200, K=800)
            gemm_mfma<bf16, float, 3><<<dim3(gm, 2), 256, 0, stream>>>(
                xz, 800, f2w, f2b_, m, 200, 200, 800);
            // h = ln(f2 + h)
            ln_res_kernel<<<rc / 4, 256, 0, stream>>>(m, h, flw, flb, h, (int)rc);
        }

        write_out_kernel<<<rcDM / 256, 256, 0, stream>>>(h, (float*)d_out, b0, rcDM);
    }
}

// Round 3
// 1306.173 us; speedup vs baseline: 1.5639x; 1.1333x over previous
//
#include <hip/hip_runtime.h>
#include <hip/hip_bf16.h>

#define DM 200
#define DIE 400
#define LSEQ 256
#define NB 256

typedef __hip_bfloat16 bf16;
typedef const float* fp;
typedef __attribute__((ext_vector_type(8))) short short8;
typedef __attribute__((ext_vector_type(4))) short short4_t;
typedef __attribute__((ext_vector_type(4))) float f32x4;

__device__ __forceinline__ float b2f(bf16 x) { return __bfloat162float(x); }
__device__ __forceinline__ bf16  f2b(float x) { return __float2bfloat16(x); }

// f32 -> bf16 bits (round-to-nearest-even)
__device__ __forceinline__ unsigned short f2bbits(float f) {
    union { float f; unsigned int u; } c; c.f = f;
    unsigned int u = c.u;
    unsigned int r = (u + 0x7fffu + ((u >> 16) & 1u)) >> 16;
    return (unsigned short)r;
}
__device__ __forceinline__ void stf(float* p, float v) { *p = v; }
__device__ __forceinline__ void stf(bf16* p, float v) { *p = f2b(v); }

// ---------------- weight f32->bf16 pre-convert (5 arrays packed, both layers) ----------------
// float counts: in_proj 320000 | x_proj 36000 | out_proj 160000 | ffn1 320000 | ffn2 320000
#define W_XP_OFF 320000
#define W_OP_OFF 356000
#define W_F1_OFF 516000
#define W_F2_OFF 836000
#define W_TOTAL  1156000
#define W_BYTES  2312000

__global__ __launch_bounds__(256) void wcvt_kernel(fp a0, fp a1, fp a2, fp a3, fp a4,
                                                   bf16* __restrict__ dst) {
    int g = blockIdx.x * 256 + threadIdx.x;
    if (g >= W_TOTAL / 4) return;
    int idx = g * 4;
    const float* src;
    int off;
    if (idx < W_XP_OFF)      { src = a0; off = idx; }
    else if (idx < W_OP_OFF) { src = a1; off = idx - W_XP_OFF; }
    else if (idx < W_F1_OFF) { src = a2; off = idx - W_OP_OFF; }
    else if (idx < W_F2_OFF) { src = a3; off = idx - W_F1_OFF; }
    else                     { src = a4; off = idx - W_F2_OFF; }
    float4 v = *(const float4*)(src + off);
    short4_t o;
    o.x = (short)f2bbits(v.x); o.y = (short)f2bbits(v.y);
    o.z = (short)f2bbits(v.z); o.w = (short)f2bbits(v.w);
    *(short4_t*)((short*)dst + idx) = o;
}

// ---------------- generic f32 -> bf16 convert (for emb chunk) ----------------
__global__ __launch_bounds__(256) void cvt_kernel(const float* __restrict__ src,
                                                  bf16* __restrict__ dst, int n4) {
    int g = blockIdx.x * 256 + threadIdx.x;
    if (g >= n4) return;
    int idx = g * 4;
    float4 v = *(const float4*)(src + idx);
    short4_t o;
    o.x = (short)f2bbits(v.x); o.y = (short)f2bbits(v.y);
    o.z = (short)f2bbits(v.z); o.w = (short)f2bbits(v.w);
    *(short4_t*)((short*)dst + idx) = o;
}

// ---------------- MFMA NT GEMM: C[m,n] = sum_k A[m,k]*W[n,k] (+epilogue) ----------------
// A and W both bf16 in memory -> staging is pure short8 vector loads (no convert).
// Block tile 128(m) x 128(n), K-step 32, 4 waves in 2x2; wave subtile 64x64 = 4x4 MFMA tiles.
// EPI: 0=none, 2=gelu_exact(x+bias), 3=x+bias
template <typename TC, int EPI>
__global__ __launch_bounds__(256) void gemm_mfma(const bf16* __restrict__ A, int lda,
                                                 const bf16* __restrict__ W,
                                                 const float* __restrict__ bias,
                                                 TC* __restrict__ C, int ldc,
                                                 int N, int K) {
    constexpr int LS = 40;                       // LDS row stride in shorts (32 + 8 pad, 80 B)
    __shared__ short As[128 * LS];
    __shared__ short Bs[128 * LS];
    const int m0 = blockIdx.x * 128;
    const int n0 = blockIdx.y * 128;
    const int tid = threadIdx.x;
    const int wave = tid >> 6;
    const int lane = tid & 63;
    const int wm = (wave & 1) * 64;
    const int wn = (wave >> 1) * 64;
    const int fm = lane & 15;
    const int quad = lane >> 4;

    f32x4 acc[4][4] = {};

    const int sr = tid >> 1;                     // staging row 0..127
    const int sc = (tid & 1) * 16;               // staging col 0 / 16

    for (int k0 = 0; k0 < K; k0 += 32) {
        // stage A: 128x32, 16 shorts/thread via 2x short8
        {
            const short* src = (const short*)A + (size_t)(m0 + sr) * lda + k0 + sc;
            short* dst = As + sr * LS + sc;
            if (k0 + sc + 16 <= K) {
                *(short8*)dst = *(const short8*)src;
                *(short8*)(dst + 8) = *(const short8*)(src + 8);
            } else {
#pragma unroll
                for (int j = 0; j < 16; ++j)
                    dst[j] = (k0 + sc + j < K) ? src[j] : (short)0;
            }
        }
        // stage B(W): 128x32, mask n and k
        {
            short* dst = Bs + sr * LS + sc;
            if (n0 + sr < N) {
                const short* src = (const short*)W + (size_t)(n0 + sr) * K + k0 + sc;
                if (k0 + sc + 16 <= K) {
                    *(short8*)dst = *(const short8*)src;
                    *(short8*)(dst + 8) = *(const short8*)(src + 8);
                } else {
#pragma unroll
                    for (int j = 0; j < 16; ++j)
                        dst[j] = (k0 + sc + j < K) ? src[j] : (short)0;
                }
            } else {
#pragma unroll
                for (int j = 0; j < 16; ++j) dst[j] = 0;
            }
        }
        __syncthreads();
        short8 af[4], bfr[4];
#pragma unroll
        for (int i = 0; i < 4; ++i)
            af[i] = *(const short8*)(As + (wm + i * 16 + fm) * LS + quad * 8);
#pragma unroll
        for (int j = 0; j < 4; ++j)
            bfr[j] = *(const short8*)(Bs + (wn + j * 16 + fm) * LS + quad * 8);
#pragma unroll
        for (int i = 0; i < 4; ++i)
#pragma unroll
            for (int j = 0; j < 4; ++j)
                acc[i][j] = __builtin_amdgcn_mfma_f32_16x16x32_bf16(af[i], bfr[j], acc[i][j], 0, 0, 0);
        __syncthreads();
    }

    // epilogue: D[m = quad*4 + r][n = fm] per 16x16 tile
#pragma unroll
    for (int j = 0; j < 4; ++j) {
        int n = n0 + wn + j * 16 + fm;
        if (n >= N) continue;
        float bv = (EPI == 2 || EPI == 3) ? bias[n] : 0.f;
#pragma unroll
        for (int i = 0; i < 4; ++i) {
#pragma unroll
            for (int r = 0; r < 4; ++r) {
                int m = m0 + wm + i * 16 + quad * 4 + r;
                float v = acc[i][j][r];
                if (EPI == 2) {
                    v += bv;
                    v = 0.5f * v * (1.f + erff(v * 0.70710678118654752f));
                } else if (EPI == 3) {
                    v += bv;
                }
                stf(&C[(size_t)m * ldc + n], v);
            }
        }
    }
}

// ---------------- causal depthwise conv (k=4) + bias + silu, IN-PLACE on x-half ----------------
__global__ __launch_bounds__(256) void conv_silu_inplace(bf16* __restrict__ xz,
                                                         const float* __restrict__ cw,
                                                         const float* __restrict__ cb,
                                                         int total /* chunkB*DIE */) {
    int idx = blockIdx.x * 256 + threadIdx.x;
    if (idx >= total) return;
    int d = idx % DIE;
    int b = idx / DIE;
    float w0 = cw[d * 4 + 0];
    float w1 = cw[d * 4 + 1];
    float w2 = cw[d * 4 + 2];
    float w3 = cw[d * 4 + 3];
    float bias = cb[d];
    float x0 = 0.f, x1 = 0.f, x2 = 0.f;
    bf16* p = xz + (size_t)b * LSEQ * 800 + d;
    for (int t = 0; t < LSEQ; ++t) {
        float x = b2f(*p);
        float s = bias + w0 * x0 + w1 * x1 + w2 * x2 + w3 * x;
        x0 = x1; x1 = x2; x2 = x;
        float sig = __builtin_amdgcn_rcpf(1.f + __expf(-s));
        *p = f2b(s * sig);
        p += 800;
    }
}

// ---------------- fused selective scan, barrier-free + ping-pong pipelined ----------------
// FAST path: A[n] == -(n+1) (the problem's A_log = log(1..16)) -> dA[n] = r^(n+1),
// r = exp(-sp): 1 transcendental + ~20 muls instead of 16 transcendentals.
// Runtime-verified per thread with generic fallback, so correctness holds for any A.
template <bool FAST>
__device__ __forceinline__ void scan_body(const float* __restrict__ rp,
                                          bf16* __restrict__ xp,
                                          const float* Wr, const float* A2,
                                          float bdt, float Dv) {
    float h[16];
#pragma unroll
    for (int n = 0; n < 16; ++n) h[n] = 0.f;

    auto scan_step = [&](const float* cur, float ut, float zv, bf16* outp) {
        float dtv = bdt;
#pragma unroll
        for (int r = 0; r < 13; ++r) dtv += Wr[r] * cur[r];
        float sp = (dtv > 20.f) ? dtv : __logf(1.f + __expf(dtv));
        float du = sp * ut;
        float dA[16];
        if (FAST) {
            float r1 = __expf(-sp);
            float r2 = r1 * r1, r3 = r2 * r1, r4 = r2 * r2;
            float r5 = r4 * r1, r6 = r4 * r2, r7 = r4 * r3, r8 = r4 * r4;
            dA[0] = r1;  dA[1] = r2;  dA[2] = r3;  dA[3] = r4;
            dA[4] = r5;  dA[5] = r6;  dA[6] = r7;  dA[7] = r8;
            dA[8] = r8 * r1;  dA[9] = r8 * r2;  dA[10] = r8 * r3;  dA[11] = r8 * r4;
            dA[12] = r8 * r5; dA[13] = r8 * r6; dA[14] = r8 * r7;  dA[15] = r8 * r8;
        } else {
#pragma unroll
            for (int n = 0; n < 16; ++n) dA[n] = __expf(sp * A2[n]);
        }
        float yv = 0.f;
#pragma unroll
        for (int n = 0; n < 16; ++n) {
            h[n] = dA[n] * h[n] + du * cur[13 + n];
            yv += h[n] * cur[29 + n];
        }
        yv += ut * Dv;
        float sig = __builtin_amdgcn_rcpf(1.f + __expf(-zv));
        *outp = f2b(yv * zv * sig);
    };

    // prologue: load t=0 into buffer A
    float ca[45], cbuf[45];
#pragma unroll
    for (int j = 0; j < 45; ++j) ca[j] = rp[j];
    float utA = b2f(xp[0]);
    float zvA = b2f(xp[400]);

    for (int t = 0; t < LSEQ; t += 2) {
        // prefetch t+1 into buffer B (independent of step t compute)
#pragma unroll
        for (int j = 0; j < 45; ++j) cbuf[j] = rp[45 + j];
        float utB = b2f(xp[800]);
        float zvB = b2f(xp[1200]);

        scan_step(ca, utA, zvA, xp);

        // prefetch t+2 into buffer A
        if (t + 2 < LSEQ) {
#pragma unroll
            for (int j = 0; j < 45; ++j) ca[j] = rp[90 + j];
            utA = b2f(xp[1600]);
            zvA = b2f(xp[2000]);
        }

        scan_step(cbuf, utB, zvB, xp + 800);

        rp += 90;
        xp += 1600;
    }
}

__global__ __launch_bounds__(256) void scan_kernel(const float* __restrict__ xdbl,
                                                   bf16* __restrict__ xz,
                                                   const float* __restrict__ dt_w,
                                                   const float* __restrict__ dt_b,
                                                   const float* __restrict__ A_log,
                                                   const float* __restrict__ Dw) {
    const int b = blockIdx.x >> 1;
    const int half = blockIdx.x & 1;
    const int tid = threadIdx.x;
    if (tid >= 200) return;            // no barriers below -> legal early exit
    const int d = half * 200 + tid;

    float A2[16], Wr[13];
    bool fast = true;
#pragma unroll
    for (int n = 0; n < 16; ++n) {
        A2[n] = -__expf(A_log[d * 16 + n]);
        fast = fast && (fabsf(A2[n] + (float)(n + 1)) < 1e-3f);
    }
#pragma unroll
    for (int r = 0; r < 13; ++r) Wr[r] = dt_w[d * 13 + r];
    const float bdt = dt_b[d];
    const float Dv = Dw[d];

    const float* __restrict__ rp = xdbl + (size_t)b * LSEQ * 45;   // block-uniform -> SGPR
    bf16* __restrict__ xp = xz + (size_t)b * LSEQ * 800 + d;

    if (fast) scan_body<true>(rp, xp, Wr, A2, bdt, Dv);
    else      scan_body<false>(rp, xp, Wr, A2, bdt, Dv);
}

// ---------------- residual + layernorm over 200; emits f32 AND bf16 copies ----------------
// dstb is a DEDICATED bf16 buffer (no aliasing with xa/xb/dst except dst==xb same-row,
// which is safe: each row is read fully into registers by its owning wave before stores).
__global__ __launch_bounds__(256) void ln_res_kernel(const float* __restrict__ xa,
                                                     const float* xb,
                                                     const float* __restrict__ w,
                                                     const float* __restrict__ bias,
                                                     float* dst,
                                                     bf16* __restrict__ dstb, int rows) {
    int wave = threadIdx.x >> 6;
    int lane = threadIdx.x & 63;
    int row = blockIdx.x * 4 + wave;
    if (row >= rows) return;
    const float* pa = xa + (size_t)row * DM;
    const float* pb = xb + (size_t)row * DM;
    float v[4];
    float sum = 0.f, sq = 0.f;
#pragma unroll
    for (int i = 0; i < 4; ++i) {
        int c = lane + i * 64;
        float t = 0.f;
        if (c < DM) t = pa[c] + pb[c];
        v[i] = t;
        sum += t;
        sq += t * t;
    }
#pragma unroll
    for (int off = 32; off > 0; off >>= 1) {
        sum += __shfl_down(sum, off);
        sq += __shfl_down(sq, off);
    }
    sum = __shfl(sum, 0);
    sq = __shfl(sq, 0);
    float mu = sum * (1.f / DM);
    float var = fmaxf(sq * (1.f / DM) - mu * mu, 0.f);
    float rstd = rsqrtf(var + 1e-12f);
    float* pd = dst + (size_t)row * DM;
    bf16* pdb = dstb + (size_t)row * DM;
#pragma unroll
    for (int i = 0; i < 4; ++i) {
        int c = lane + i * 64;
        if (c < DM) {
            float o = (v[i] - mu) * rstd * w[c] + bias[c];
            pd[c] = o;
            pdb[c] = f2b(o);
        }
    }
}

// ---------------- output split for a batch chunk (f32 out) ----------------
__global__ __launch_bounds__(256) void write_out_kernel(const float* __restrict__ h,
                                                        float* __restrict__ out,
                                                        int b0, int total /* rc*DM */) {
    int idx = blockIdx.x * 256 + threadIdx.x;
    if (idx >= total) return;
    int d = idx % DM;
    int bl = idx / DM;
    int l = bl % LSEQ;
    int b = b0 + bl / LSEQ;
    float v = h[idx];
    if (l == LSEQ - 1) {
        out[b * DM + d] = v;
    } else {
        out[(size_t)NB * DM + ((size_t)(b * (LSEQ - 1) + l) * DM + d)] = v;
    }
}

extern "C" void kernel_launch(void* const* d_in, const int* in_sizes, int n_in,
                              void* d_out, int out_size, void* d_ws, size_t ws_size,
                              hipStream_t stream) {
    fp emb       = (fp)d_in[0];
    fp in_proj_w = (fp)d_in[2];
    fp conv_w    = (fp)d_in[3];
    fp conv_b    = (fp)d_in[4];
    fp x_proj_w  = (fp)d_in[5];
    fp dt_proj_w = (fp)d_in[6];
    fp dt_proj_b = (fp)d_in[7];
    fp A_log     = (fp)d_in[8];
    fp Dw        = (fp)d_in[9];
    fp out_proj_w= (fp)d_in[10];
    fp ln1_w     = (fp)d_in[11];
    fp ln1_b     = (fp)d_in[12];
    fp ffn_w1    = (fp)d_in[13];
    fp ffn_b1    = (fp)d_in[14];
    fp ffn_w2    = (fp)d_in[15];
    fp ffn_b2    = (fp)d_in[16];
    fp ffn_ln_w  = (fp)d_in[17];
    fp ffn_ln_b  = (fp)d_in[18];

    // workspace layout (per-row bytes 3780 + weights + slack):
    // [ wb bf16 W_BYTES | xz rc*1600 | hb rc*400 | xdbl rc*180 | m rc*800 | h rc*800 ]
    const int cands[8] = {256, 128, 64, 32, 16, 8, 4, 2};
    int cb = 2;
    for (int ci = 0; ci < 8; ++ci) {
        size_t rcx = (size_t)cands[ci] * LSEQ;
        if (rcx * 3780 + W_BYTES + 1024 <= ws_size) { cb = cands[ci]; break; }
    }
    const size_t rc = (size_t)cb * LSEQ;

    bf16*  wb   = (bf16*)d_ws;                     // packed bf16 weights
    bf16*  xz   = (bf16*)((char*)d_ws + W_BYTES);  // rc*800 bf16
    bf16*  hb   = xz + rc * 800;                   // rc*200 bf16 (GEMM-A activation copy)
    float* xdbl = (float*)(hb + rc * 200);         // rc*45 f32
    float* m    = xdbl + rc * 45;                  // rc*200 f32
    float* h    = m + rc * 200;                    // rc*200 f32

    // pre-convert all GEMM weights to bf16 (once per launch)
    wcvt_kernel<<<(W_TOTAL / 4 + 255) / 256, 256, 0, stream>>>(
        in_proj_w, x_proj_w, out_proj_w, ffn_w1, ffn_w2, wb);

    const int rcDM = (int)rc * DM;
    const int gm = (int)rc / 128;              // m-tiles

    for (int b0 = 0; b0 < NB; b0 += cb) {
        const float* emb_chunk = emb + (size_t)b0 * LSEQ * DM;

        // emb chunk -> bf16 into hb
        cvt_kernel<<<(rcDM / 4 + 255) / 256, 256, 0, stream>>>(emb_chunk, hb, rcDM / 4);

        for (int i = 0; i < 2; ++i) {
            const bf16* wb_in = wb + (size_t)i * 160000;
            const bf16* wb_xp = wb + W_XP_OFF + (size_t)i * 18000;
            const bf16* wb_op = wb + W_OP_OFF + (size_t)i * 80000;
            const bf16* wb_f1 = wb + W_F1_OFF + (size_t)i * 160000;
            const bf16* wb_f2 = wb + W_F2_OFF + (size_t)i * 160000;
            fp cw    = conv_w + (size_t)i * 400 * 4;
            fp cbp   = conv_b + (size_t)i * 400;
            fp w_dt  = dt_proj_w + (size_t)i * 400 * 13;
            fp b_dt  = dt_proj_b + (size_t)i * 400;
            fp Ai    = A_log + (size_t)i * 400 * 16;
            fp Di    = Dw + (size_t)i * 400;
            fp l1w   = ln1_w + (size_t)i * 200;
            fp l1b   = ln1_b + (size_t)i * 200;
            fp f1b   = ffn_b1 + (size_t)i * 800;
            fp f2b_  = ffn_b2 + (size_t)i * 200;
            fp flw   = ffn_ln_w + (size_t)i * 200;
            fp flb   = ffn_ln_b + (size_t)i * 200;

            const float* hin = (i == 0) ? emb_chunk : h;   // f32 residual source

            // xz = hin @ in_proj^T   (N=800, K=200); A = bf16 copy in hb
            gemm_mfma<bf16, 0><<<dim3(gm, 7), 256, 0, stream>>>(
                hb, 200, wb_in, nullptr, xz, 800, 800, 200);
            // conv + silu in-place on x-half
            conv_silu_inplace<<<(cb * DIE + 255) / 256, 256, 0, stream>>>(xz, cw, cbp, cb * DIE);
            // xdbl = xc @ x_proj^T   (N=45, K=400)
            gemm_mfma<float, 0><<<dim3(gm, 1), 256, 0, stream>>>(
                xz, 800, wb_xp, nullptr, xdbl, 45, 45, 400);
            // fused scan; y in-place on x-half
            scan_kernel<<<cb * 2, 256, 0, stream>>>(xdbl, xz, w_dt, b_dt, Ai, Di);
            // m = y @ out_proj^T   (N=200, K=400)
            gemm_mfma<float, 0><<<dim3(gm, 2), 256, 0, stream>>>(
                xz, 800, wb_op, nullptr, m, 200, 200, 400);
            // h = ln(m + hin), f32 into h + bf16 into hb
            ln_res_kernel<<<rc / 4, 256, 0, stream>>>(m, hin, l1w, l1b, h, hb, (int)rc);
            // f1 = gelu(h @ w1^T + b1) -> xz  (A = bf16 h in hb)
            gemm_mfma<bf16, 2><<<dim3(gm, 7), 256, 0, stream>>>(
                hb, 200, wb_f1, f1b, xz, 800, 800, 200);
            // f2 = f1 @ w2^T + b2 -> m   (N=200, K=800)
            gemm_mfma<float, 3><<<dim3(gm, 2), 256, 0, stream>>>(
                xz, 800, wb_f2, f2b_, m, 200, 200, 800);
            // h = ln(f2 + h) in-place (same-row safe) + bf16 into hb (next layer's A)
            ln_res_kernel<<<rc / 4, 256, 0, stream>>>(m, h, flw, flb, h, hb, (int)rc);
        }

        write_out_kernel<<<rcDM / 256, 256, 0, stream>>>(h, (float*)d_out, b0, rcDM);
    }
}